// Round 5
// baseline (675.336 us; speedup 1.0000x reference)
//
#include <hip/hip_runtime.h>
#include <math.h>

#define LL    2048
#define DD    512
#define CD    21
#define CLIPD 10
#define NT    256

typedef __attribute__((ext_vector_type(8))) short bf16x8;
typedef __attribute__((ext_vector_type(4))) float f32x4;

typedef __attribute__((address_space(3))) unsigned int        as3_u32;
typedef const __attribute__((address_space(1))) unsigned int  as1_u32;

__device__ __forceinline__ void dma16(const void* g, void* l) {
    __builtin_amdgcn_global_load_lds((as1_u32*)g, (as3_u32*)l, 16, 0, 0);
}

__device__ __forceinline__ unsigned short bf16_rn(float x) {
    union { float f; unsigned u; } v; v.f = x;
    return (unsigned short)((v.u + 0x7FFFu + ((v.u >> 16) & 1u)) >> 16);
}
__device__ __forceinline__ float bf16_f(unsigned short h) {
    union { float f; unsigned u; } v; v.u = ((unsigned)h) << 16;
    return v.f;
}

// ---------- kernel A: fused convert (fp32 -> tiled bf16 hi/lo) + kp ----------
// Tiled layout (consumed by GEMM DMA), unchanged from R4:
//   chunk c = (((b*16 + rblk)*16 + kt)*8 + g)*64 + lane
//   row_in_128 = g*16 + (lane&15),  k = kt*32 + (lane>>4)*8 .. +7
// Block handles 64 rows (half a 128-row tile): r0 = rblk*128 + h*64, g = h*4 + wave.
__global__ __launch_bounds__(256) void convert_kp_kernel(
    const float* __restrict__ key,            // [B, L, D]
    const float* __restrict__ params,         // [C, D]
    unsigned short* __restrict__ khi,
    unsigned short* __restrict__ klo,
    float* __restrict__ kp)                   // [B, L, C]
{
    __shared__ float4 pL[CD * (DD / 4)];      // 43008 B  (params, c-major)
    __shared__ float4 As4[64 * 33];           // 33792 B  (64 rows x 128 k, stride 33 float4)

    const int t    = threadIdx.x;
    const int rb2  = blockIdx.x;              // 0..31
    const int b    = blockIdx.y;              // 0..15
    const int rblk = rb2 >> 1;
    const int h    = rb2 & 1;
    const int r0   = rblk * 128 + h * 64;

    for (int idx = t; idx < CD * (DD / 4); idx += 256)
        pL[idx] = ((const float4*)params)[idx];
    // pL consumed only after the first in-loop __syncthreads

    const int w = t >> 6, lane = t & 63;

    float acc[CD];
    #pragma unroll
    for (int c = 0; c < CD; ++c) acc[c] = 0.f;

    const float4* key4 = (const float4*)key + ((size_t)b * LL + r0) * (DD / 4);

    for (int ks = 0; ks < 4; ++ks) {          // 128-k stages
        if (ks) __syncthreads();              // protect As while prior stage in use
        // ---- stage 64 rows x 128 k, coalesced (lanes 0-31 = one row's 512 B) ----
        #pragma unroll
        for (int j = 0; j < 8; ++j) {
            const int flat = t + 256 * j;     // 0..2047
            const int row  = flat >> 5;       // 0..63
            const int kq   = flat & 31;       // float4 within 128-k stage
            As4[row * 33 + kq] = key4[(size_t)row * (DD / 4) + ks * 32 + kq];
        }
        __syncthreads();

        // ---- convert & write 4 chunks per thread (coalesced 1 KB/wave stores) ----
        #pragma unroll
        for (int j = 0; j < 4; ++j) {
            const int kt  = ks * 4 + j;
            const int g   = h * 4 + w;
            const int row = w * 16 + (lane & 15);           // local row
            const int kl  = j * 32 + (lane >> 4) * 8;       // local k (0..127)
            const float4 v0 = As4[row * 33 + (kl >> 2)];
            const float4 v1 = As4[row * 33 + (kl >> 2) + 1];
            const float vv[8] = {v0.x, v0.y, v0.z, v0.w, v1.x, v1.y, v1.z, v1.w};
            unsigned short hh[8], ll[8];
            #pragma unroll
            for (int e = 0; e < 8; ++e) {
                hh[e] = bf16_rn(vv[e]);
                ll[e] = bf16_rn(vv[e] - bf16_f(hh[e]));
            }
            const size_t c = ((((size_t)b * 16 + rblk) * 16 + kt) * 8 + g) * 64 + lane;
            *(bf16x8*)(khi + c * 8) = *(const bf16x8*)hh;
            *(bf16x8*)(klo + c * 8) = *(const bf16x8*)ll;
        }

        // ---- kp partials: wave 0, one row per lane, params broadcast ----
        if (t < 64) {
            #pragma unroll 8
            for (int kq = 0; kq < 32; ++kq) {
                const float4 a = As4[t * 33 + kq];
                #pragma unroll
                for (int c = 0; c < CD; ++c) {
                    const float4 p = pL[c * 128 + ks * 32 + kq];
                    acc[c] += a.x * p.x + a.y * p.y + a.z * p.z + a.w * p.w;
                }
            }
        }
    }

    if (t < 64) {
        float* dst = kp + ((size_t)b * LL + r0 + t) * CD;
        #pragma unroll
        for (int c = 0; c < CD; ++c) dst[c] = acc[c];
    }
}

// ---------- kernel B: GEMM from pre-tiled bf16 via global_load_lds ----------
__global__ __launch_bounds__(NT) void gemm_mfma_dma_kernel(
    const unsigned short* __restrict__ khi,
    const unsigned short* __restrict__ klo,
    const int*   __restrict__ mask,          // [B, L]
    const float* __restrict__ kp,            // [B, L, C]
    float*       __restrict__ out)           // [B, L, L]
{
    __shared__ unsigned short tiles[4][4096];   // Ah, Al, Bh, Bl : 8 KB each (32 KB)

    const int t  = threadIdx.x;
    const int bz = blockIdx.z;
    const int i0 = blockIdx.y * 128;
    const int j0 = blockIdx.x * 128;

    const int lane = t & 63, wave = t >> 6;
    const int wr = wave >> 1, wc = wave & 1;
    const int quad = lane >> 4, l16 = lane & 15;

    // wave w stages plane-tile w: 0=Ah 1=Al 2=Bh 3=Bl
    const unsigned short* plane = (wave & 1) ? klo : khi;
    const int rblk = (wave < 2) ? blockIdx.y : blockIdx.x;
    const unsigned short* gbase = plane + ((size_t)bz * 16 + rblk) * 16 * 4096;
    unsigned short* lbase = &tiles[wave][0];

    f32x4 acc[4][4];
    #pragma unroll
    for (int mt = 0; mt < 4; ++mt)
        #pragma unroll
        for (int nt = 0; nt < 4; ++nt)
            acc[mt][nt] = (f32x4){0.f, 0.f, 0.f, 0.f};

    for (int kt = 0; kt < DD / 32; ++kt) {
        const unsigned short* gt = gbase + (size_t)kt * 4096;
        #pragma unroll
        for (int seg = 0; seg < 8; ++seg)
            dma16(gt + seg * 512 + lane * 8, lbase + seg * 512);
        __syncthreads();

        bf16x8 fah[4], fal[4], fbh[4], fbl[4];
        #pragma unroll
        for (int x = 0; x < 4; ++x) {
            const int ga = ((wr * 4 + x) * 64 + lane) * 8;
            const int gb = ((wc * 4 + x) * 64 + lane) * 8;
            fah[x] = *(const bf16x8*)&tiles[0][ga];
            fal[x] = *(const bf16x8*)&tiles[1][ga];
            fbh[x] = *(const bf16x8*)&tiles[2][gb];
            fbl[x] = *(const bf16x8*)&tiles[3][gb];
        }

        #pragma unroll
        for (int mt = 0; mt < 4; ++mt)
            #pragma unroll
            for (int nt = 0; nt < 4; ++nt) {
                acc[mt][nt] = __builtin_amdgcn_mfma_f32_16x16x32_bf16(fah[mt], fbh[nt], acc[mt][nt], 0, 0, 0);
                acc[mt][nt] = __builtin_amdgcn_mfma_f32_16x16x32_bf16(fah[mt], fbl[nt], acc[mt][nt], 0, 0, 0);
                acc[mt][nt] = __builtin_amdgcn_mfma_f32_16x16x32_bf16(fal[mt], fbh[nt], acc[mt][nt], 0, 0, 0);
            }
        __syncthreads();
    }

    // ---- epilogue: bias (global kp) + mask + store ----
    const int* maskb = mask + (size_t)bz * LL;
    int mkv[4];
    #pragma unroll
    for (int nt = 0; nt < 4; ++nt)
        mkv[nt] = maskb[j0 + wc * 64 + nt * 16 + l16];

    const float* kpb = kp + (size_t)bz * LL * CD;
    const bool uni = (j0 - i0 >= 256) || (i0 - j0 >= 256);   // block-uniform rel saturation
    const int  uc  = (j0 > i0) ? (2 * CLIPD) : 0;

    #pragma unroll
    for (int mt = 0; mt < 4; ++mt)
        #pragma unroll
        for (int r = 0; r < 4; ++r) {
            const int li   = wr * 64 + mt * 16 + quad * 4 + r;
            const int grow = i0 + li;
            float* orow = out + ((size_t)bz * LL + grow) * LL;
            const float* kprow = kpb + (size_t)grow * CD;
            if (uni) {
                const float bias = kprow[uc];
                #pragma unroll
                for (int nt = 0; nt < 4; ++nt) {
                    const int col = j0 + wc * 64 + nt * 16 + l16;
                    const float v = acc[mt][nt][r] + bias;
                    orow[col] = mkv[nt] ? -1e20f : v;
                }
            } else {
                #pragma unroll
                for (int nt = 0; nt < 4; ++nt) {
                    const int col = j0 + wc * 64 + nt * 16 + l16;
                    int rel = col - grow;
                    rel = rel < -CLIPD ? -CLIPD : (rel > CLIPD ? CLIPD : rel);
                    const float v = acc[mt][nt][r] + kprow[rel + CLIPD];
                    orow[col] = mkv[nt] ? -1e20f : v;
                }
            }
        }
}

// ---------- kernel C: in-place row softmax ----------
__global__ __launch_bounds__(256) void softmax_kernel(float* __restrict__ out) {
    const int row  = blockIdx.x * 4 + (threadIdx.x >> 6);
    const int lane = threadIdx.x & 63;
    float4* r4 = (float4*)out + (size_t)row * (LL / 4);

    float4 v[8];
    float mx = -INFINITY;
    #pragma unroll
    for (int c = 0; c < 8; ++c) {
        v[c] = r4[lane + 64 * c];
        mx = fmaxf(mx, fmaxf(fmaxf(v[c].x, v[c].y), fmaxf(v[c].z, v[c].w)));
    }
    #pragma unroll
    for (int off = 32; off; off >>= 1) mx = fmaxf(mx, __shfl_xor(mx, off));

    float s = 0.f;
    #pragma unroll
    for (int c = 0; c < 8; ++c) {
        v[c].x = __expf(v[c].x - mx); v[c].y = __expf(v[c].y - mx);
        v[c].z = __expf(v[c].z - mx); v[c].w = __expf(v[c].w - mx);
        s += v[c].x + v[c].y + v[c].z + v[c].w;
    }
    #pragma unroll
    for (int off = 32; off; off >>= 1) s += __shfl_xor(s, off);

    const float inv = 1.0f / s;
    #pragma unroll
    for (int c = 0; c < 8; ++c) {
        v[c].x *= inv; v[c].y *= inv; v[c].z *= inv; v[c].w *= inv;
        r4[lane + 64 * c] = v[c];
    }
}

extern "C" void kernel_launch(void* const* d_in, const int* in_sizes, int n_in,
                              void* d_out, int out_size, void* d_ws, size_t ws_size,
                              hipStream_t stream) {
    const float* key    = (const float*)d_in[0];
    const int*   mask   = (const int*)d_in[1];
    const float* params = (const float*)d_in[2];
    float*       out    = (float*)d_out;

    const int B = in_sizes[0] / (LL * DD);        // 16
    const int nrows = B * LL;                     // 32768

    const size_t kp_bytes    = (size_t)nrows * CD * sizeof(float);   // 2.75 MB
    const size_t plane_elems = (size_t)B * LL * DD;                  // 16.8M

    float*          kp  = (float*)d_ws;
    unsigned short* khi = (unsigned short*)((char*)d_ws + kp_bytes);
    unsigned short* klo = khi + plane_elems;

    convert_kp_kernel<<<dim3(32, B), dim3(256), 0, stream>>>(key, params, khi, klo, kp);

    dim3 ggrid(LL / 128, LL / 128, B);            // 16 x 16 x 16
    gemm_mfma_dma_kernel<<<ggrid, dim3(NT), 0, stream>>>(khi, klo, mask, kp, out);

    softmax_kernel<<<dim3(nrows / 4), dim3(256), 0, stream>>>(out);
}